// Round 1
// 139.868 us; speedup vs baseline: 1.0921x; 1.0921x over previous
//
#include <hip/hip_runtime.h>
#include <stdint.h>

using short8  = __attribute__((ext_vector_type(8))) short;   // 8 bf16 = 4 VGPRs
using f32x4   = __attribute__((ext_vector_type(4))) float;
using float4v = __attribute__((ext_vector_type(4))) float;
using u16x4   = __attribute__((ext_vector_type(4))) unsigned short;

__device__ __forceinline__ unsigned short f2b(float f) {
    union { float f; unsigned int i; } v; v.f = f;
    unsigned int i = v.i;
    unsigned int r = (i + 0x7fffu + ((i >> 16) & 1u)) >> 16;   // RNE
    return (unsigned short)r;
}
__device__ __forceinline__ short8 ld8(const unsigned short* p) {
    return *reinterpret_cast<const short8*>(p);
}
__device__ __forceinline__ void st8(unsigned short* p, short8 v) {
    *reinterpret_cast<short8*>(p) = v;
}
// A-operand load: 8 elements -> bf16x8 (identity for bf16, convert for fp32)
__device__ __forceinline__ short8 ldA(const unsigned short* p) { return ld8(p); }
__device__ __forceinline__ short8 ldA(const float* p) {
    float4v v0 = *reinterpret_cast<const float4v*>(p);
    float4v v1 = *reinterpret_cast<const float4v*>(p + 4);
    short8 o;
#pragma unroll
    for (int j = 0; j < 4; ++j) o[j] = (short)f2b(v0[j]);
#pragma unroll
    for (int j = 0; j < 4; ++j) o[4 + j] = (short)f2b(v1[j]);
    return o;
}
__device__ __forceinline__ f32x4 mfma16(short8 a, short8 b, f32x4 c) {
    return __builtin_amdgcn_mfma_f32_16x16x32_bf16(a, b, c, 0, 0, 0);
}
__device__ __forceinline__ void stC(float* p, float v)          { *p = v; }
__device__ __forceinline__ void stC(unsigned short* p, float v) { *p = f2b(v); }

// pack two f32 -> one u32 of 2 bf16 (RNE), single VALU op
__device__ __forceinline__ unsigned int cvtpk(float lo, float hi) {
    unsigned int r;
    asm("v_cvt_pk_bf16_f32 %0, %1, %2" : "=v"(r) : "v"(lo), "v"(hi));
    return r;
}
// v_permlane32_swap_b32: vdst[32:63] <-> vsrc[0:31]
__device__ __forceinline__ void pl32swap(unsigned int& a, unsigned int& b) {
    asm("v_permlane32_swap_b32 %0, %1" : "+v"(a), "+v"(b));
}
// v_permlane16_swap_b32: vdst odd 16-rows <-> vsrc even 16-rows
__device__ __forceinline__ void pl16swap(unsigned int& a, unsigned int& b) {
    asm("v_permlane16_swap_b32 %0, %1" : "+v"(a), "+v"(b));
}
__device__ __forceinline__ short8 pack4(unsigned int x0, unsigned int x1,
                                        unsigned int x2, unsigned int x3) {
    union { unsigned int u[4]; short8 s; } c;
    c.u[0] = x0; c.u[1] = x1; c.u[2] = x2; c.u[3] = x3;
    return c.s;
}

// ---------------------------------------------------------------------------
// Stage 1: style[map][b][i] = dot(s[b,:], aff_w[i,:]) + aff_b[i]   (fp32)
// ---------------------------------------------------------------------------
__global__ __launch_bounds__(256) void style_kernel(
    const float* __restrict__ s,
    const float* __restrict__ k_aff_w, const float* __restrict__ k_aff_b,
    const float* __restrict__ o_aff_w, const float* __restrict__ o_aff_b,
    float* __restrict__ style)
{
    int wid  = blockIdx.x * 4 + (threadIdx.x >> 6);
    int lane = threadIdx.x & 63;
    int map  = wid >> 12;
    int rem  = wid & 4095;
    int b    = rem >> 9;
    int i    = rem & 511;
    const float* aw = map ? o_aff_w : k_aff_w;
    const float* ab = map ? o_aff_b : k_aff_b;
    const float* sp = s  + b * 512 + lane * 8;
    const float* wp = aw + i * 512 + lane * 8;
    float acc = 0.f;
#pragma unroll
    for (int j = 0; j < 8; ++j) acc += sp[j] * wp[j];
#pragma unroll
    for (int off = 1; off < 64; off <<= 1) acc += __shfl_xor(acc, off, 64);
    if (lane == 0) style[(map * 8 + b) * 512 + i] = acc + ab[i];
}

// ---------------------------------------------------------------------------
// Stage 2: wmod[map][b][o][i] = bf16( weight[o][i]*style[map][b][i] * demod )
// ---------------------------------------------------------------------------
__global__ __launch_bounds__(256) void modw_kernel(
    const float* __restrict__ k_weight,
    const float* __restrict__ o_weight,
    const float* __restrict__ style,
    unsigned short* __restrict__ wmod)
{
    int wid  = blockIdx.x * 4 + (threadIdx.x >> 6);
    int lane = threadIdx.x & 63;
    int map  = wid >> 12;
    int rem  = wid & 4095;
    int b    = rem >> 9;
    int o    = rem & 511;
    const float* wrow = (map ? o_weight : k_weight) + o * 512 + lane * 8;
    const float* st   = style + (map * 8 + b) * 512 + lane * 8;
    float w[8]; float ss = 0.f;
#pragma unroll
    for (int j = 0; j < 8; ++j) { w[j] = wrow[j] * st[j]; ss += w[j] * w[j]; }
#pragma unroll
    for (int off = 1; off < 64; off <<= 1) ss += __shfl_xor(ss, off, 64);
    float demod = rsqrtf(ss + 1e-8f);
    short8 ov;
#pragma unroll
    for (int j = 0; j < 8; ++j) ov[j] = (short)f2b(w[j] * demod);
    unsigned short* dst = wmod + (((size_t)map * 8 + b) * 512 + o) * 512 + lane * 8;
    *reinterpret_cast<short8*>(dst) = ov;
}

// ---------------------------------------------------------------------------
// Stage 3/5 (R11): batched GEMM — R9 structure (best measured) + fused cvt.
// C[b][m][n] = sum_k A[b][m][k] * Bt[b][n][k];  M=1024, N=512, K=512, B=8.
// AT=float (GEMM1): reads fp32 x directly, converts to bf16 during staging
// (deletes the cvt dispatch + 24 MB round-trip). AT=ushort (GEMM2): as R9.
//  - b = blk&7: batch-per-XCD L2 locality (R9-measured win)
//  - BK=64, depth-2 prefetch: ds_write commit consumes registers loaded one
//    full iteration earlier -> vmcnt waits hit completed loads
// Tile 64x64, 4 waves (2x2), wave tile 32x32. KP=72 (144B rows, 16B-aligned
// — R7 lesson; 2-way frag-read aliasing only). LDS 36 KB, grid 1024.
// WVT: fused epilogue writes VT[b*8+nt][d][token] via in-LDS transpose.
// ---------------------------------------------------------------------------
template <typename AT, typename CT, bool WVT>
__global__ __launch_bounds__(256) void gemm_bt_lds_kernel(
    const AT* __restrict__ A,
    const unsigned short* __restrict__ Bt,
    CT* __restrict__ C,
    unsigned short* __restrict__ VT)
{
    constexpr int KP = 72;
    constexpr int TP = 72;    // Tt row: 144 B (16B multiple)
    __shared__ __align__(16) unsigned short smem[4 * 64 * KP];   // 36 KB
    typedef unsigned short Plane[64][KP];
    Plane* As = reinterpret_cast<Plane*>(smem);                  // [2][64][KP]
    Plane* Bs = reinterpret_cast<Plane*>(smem + 2 * 64 * KP);    // [2][64][KP]

    int blk = blockIdx.x;
    int b   = blk & 7;            // XCD = batch
    int rem = blk >> 3;
    int mt  = rem & 15;
    int nt  = rem >> 4;           // 0..7
    int tid  = threadIdx.x;
    int w    = tid >> 6;
    int lane = tid & 63;
    int quad = lane >> 4;
    int r    = lane & 15;
    int wm   = w >> 1;            // 0..1 (M half)
    int wn   = w & 1;             // 0..1 (N half)

    const AT*             Ab = A  + ((size_t)b * 1024 + mt * 64) * 512;
    const unsigned short* Bb = Bt + ((size_t)b * 512  + nt * 64) * 512;

    // staging: thread t covers row t>>2 (0..63), element chunks (t&3)*8 and +32
    int srow = tid >> 2;
    int scol = (tid & 3) * 8;
    const AT*             ga = Ab + (size_t)srow * 512 + scol;
    const unsigned short* gb = Bb + (size_t)srow * 512 + scol;

    f32x4 acc[2][2];
#pragma unroll
    for (int i = 0; i < 2; ++i)
#pragma unroll
        for (int j = 0; j < 2; ++j) acc[i][j] = f32x4{0.f, 0.f, 0.f, 0.f};

    short8 rg[2][4];   // [tile parity][a-lo, a-hi, b-lo, b-hi]

    // prologue: tile 0 direct to LDS buf 0; tile 1 into rg[1]
    st8(&As[0][srow][scol],      ldA(ga));
    st8(&As[0][srow][scol + 32], ldA(ga + 32));
    st8(&Bs[0][srow][scol],      ld8(gb));
    st8(&Bs[0][srow][scol + 32], ld8(gb + 32));
    rg[1][0] = ldA(ga + 64);  rg[1][1] = ldA(ga + 96);
    rg[1][2] = ld8(gb + 64);  rg[1][3] = ld8(gb + 96);
    __syncthreads();

#pragma unroll
    for (int ks = 0; ks < 8; ++ks) {
        int s = ks & 1;
        if (ks < 6) {                         // load tile ks+2 (consumed next iter)
            int ko = (ks + 2) * 64;
            rg[s][0] = ldA(ga + ko);       rg[s][1] = ldA(ga + ko + 32);
            rg[s][2] = ld8(gb + ko);       rg[s][3] = ld8(gb + ko + 32);
        }
#pragma unroll
        for (int kh = 0; kh < 2; ++kh) {
            short8 af[2], bf[2];
#pragma unroll
            for (int i = 0; i < 2; ++i)
                af[i] = ld8(&As[s][wm * 32 + i * 16 + r][kh * 32 + quad * 8]);
#pragma unroll
            for (int j = 0; j < 2; ++j)
                bf[j] = ld8(&Bs[s][wn * 32 + j * 16 + r][kh * 32 + quad * 8]);
#pragma unroll
            for (int i = 0; i < 2; ++i)
#pragma unroll
                for (int j = 0; j < 2; ++j)
                    acc[i][j] = mfma16(af[i], bf[j], acc[i][j]);
        }
        if (ks < 7) {                         // commit tile ks+1 (loaded last iter)
            int ns = s ^ 1;
            st8(&As[ns][srow][scol],      rg[ns][0]);
            st8(&As[ns][srow][scol + 32], rg[ns][1]);
            st8(&Bs[ns][srow][scol],      rg[ns][2]);
            st8(&Bs[ns][srow][scol + 32], rg[ns][3]);
        }
        __syncthreads();
    }

    CT* Cb = C + (size_t)b * 1024 * 512;
#pragma unroll
    for (int i = 0; i < 2; ++i)
#pragma unroll
        for (int rr = 0; rr < 4; ++rr) {
            int row = mt * 64 + wm * 32 + i * 16 + quad * 4 + rr;
#pragma unroll
            for (int j = 0; j < 2; ++j) {
                int col = nt * 64 + wn * 32 + j * 16 + r;
                stC(Cb + (size_t)row * 512 + col, acc[i][j][rr]);
            }
        }
    if (WVT) {
        // last K-iteration ended at a barrier: smem reusable
        unsigned short (*Tt)[TP] = reinterpret_cast<unsigned short (*)[TP]>(smem);
#pragma unroll
        for (int i = 0; i < 2; ++i)
#pragma unroll
            for (int j = 0; j < 2; ++j) {
                int d = wn * 32 + j * 16 + r;
#pragma unroll
                for (int rh = 0; rh < 2; ++rh) {
                    int tok = wm * 32 + i * 16 + quad * 4 + rh * 2;
                    unsigned int pv = (unsigned int)f2b(acc[i][j][rh * 2]) |
                                      ((unsigned int)f2b(acc[i][j][rh * 2 + 1]) << 16);
                    *reinterpret_cast<unsigned int*>(&Tt[d][tok]) = pv;
                }
            }
        __syncthreads();
        int d  = tid >> 2;          // 0..63
        int cc = tid & 3;           // token chunk of 16
        const unsigned short* src = &Tt[d][cc * 16];
        unsigned short* dst = VT + ((size_t)(b * 8 + nt) * 64 + d) * 1024 + mt * 64 + cc * 16;
        short8 t0 = ld8(src), t1 = ld8(src + 8);
        st8(dst,     t0);
        st8(dst + 8, t1);
    }
}

// ---------------------------------------------------------------------------
// Stage 4 (R12): flash attention — in-register P repack (T12).
// Changes vs R5/R8 frozen config:
//  - plds (9.2 KB) DELETED: P goes f32 -> v_cvt_pk_bf16_f32 pairs ->
//    permlane32_swap + permlane16_swap -> MFMA A-fragments, no LDS round-trip.
//    Derivation (verified quad-by-quad): lane(r,q) holds S^T pair index
//    M = 8t + 2q + h; A-fragment needs pairs 4q+j. For each half:
//    (ap_j0, ap_j2) = pl16swap(pl32swap(pk[t_lo][h], pk[t_hi][h])).
//  - LDS 46080 -> 36864 B: 3 -> 4 blocks/CU; grid 1024 = exactly 4/CU,
//    all blocks co-resident (kills the 25% dispatch tail).
// Unchanged: PAD=72, 16 q-rows/wave, grid 1024, static-max softmax,
// cooperative K/V staging + VGPR prefetch.
// ---------------------------------------------------------------------------
__global__ __launch_bounds__(256) void attn_kernel(
    const unsigned short* __restrict__ kqv,
    const unsigned short* __restrict__ vt,
    unsigned short* __restrict__ attn_out)
{
    constexpr int PAD = 72;
    int blk = blockIdx.x;
    int bh = blk & 63;            // XCD-locality: same bh every 64 blocks
    int qt = blk >> 6;            // 0..15
    int b  = bh >> 3, h = bh & 7;
    int tid  = threadIdx.x;
    int lane = tid & 63;
    int quad = lane >> 4;
    int r    = lane & 15;

    __shared__ __align__(16) unsigned short klds[2][64][PAD];
    __shared__ __align__(16) unsigned short vlds[2][64][PAD];

    const unsigned short* Mb = kqv + (size_t)b * 1024 * 512;
    int wv = tid >> 6;
    int q0 = qt * 64 + wv * 16;

    const unsigned short* qptr = Mb + (size_t)(q0 + r) * 512 + h * 64 + quad * 8;
    short8 bq0 = ld8(qptr);
    short8 bq1 = ld8(qptr + 32);

    short8 ones;
#pragma unroll
    for (int j = 0; j < 8; ++j) ones[j] = (short)0x3F80;   // bf16 1.0

    f32x4 o0 = {0.f, 0.f, 0.f, 0.f};
    f32x4 o1 = o0, o2 = o0, o3 = o0, lacc = o0;

    int srow0 = tid >> 3;
    int srow1 = srow0 + 32;
    int scol  = (tid & 7) * 8;
    const unsigned short* Kg = Mb + h * 64;
    const unsigned short* Vg = vt + (size_t)bh * 64 * 1024;

    {
        short8 k0v = ld8(Kg + (size_t)srow0 * 512 + scol);
        short8 k1v = ld8(Kg + (size_t)srow1 * 512 + scol);
        short8 v0v = ld8(Vg + (size_t)srow0 * 1024 + scol);
        short8 v1v = ld8(Vg + (size_t)srow1 * 1024 + scol);
        st8(&klds[0][srow0][scol], k0v);
        st8(&klds[0][srow1][scol], k1v);
        st8(&vlds[0][srow0][scol], v0v);
        st8(&vlds[0][srow1][scol], v1v);
    }
    __syncthreads();

    const float c  = 0.18033688011112042f;   // (1/8) * log2(e)
    const float CM = 28.853900817779268f;    // 20 * log2(e)

    for (int it = 0; it < 16; ++it) {
        int s = it & 1;
        short8 pk0, pk1, pv0, pv1;
        if (it < 15) {
            int k0n = (it + 1) * 64;
            pk0 = ld8(Kg + (size_t)(k0n + srow0) * 512 + scol);
            pk1 = ld8(Kg + (size_t)(k0n + srow1) * 512 + scol);
            pv0 = ld8(Vg + (size_t)srow0 * 1024 + k0n + scol);
            pv1 = ld8(Vg + (size_t)srow1 * 1024 + k0n + scol);
        }
        // ---- S^T: lane holds 16 scores for q-col r (k = 16t + 4*quad + rr)
        f32x4 st_[4];
#pragma unroll
        for (int t = 0; t < 4; ++t) {
            short8 ka = ld8(&klds[s][t * 16 + r][quad * 8]);
            short8 kb = ld8(&klds[s][t * 16 + r][32 + quad * 8]);
            f32x4 sacc = {0.f, 0.f, 0.f, 0.f};
            sacc = mfma16(ka, bq0, sacc);
            sacc = mfma16(kb, bq1, sacc);
            st_[t] = sacc;
        }
        // ---- P = exp2(s*c - CM) -> bf16 pairs, in-register repack to A-frags
        unsigned int pk_[4][2];
#pragma unroll
        for (int t = 0; t < 4; ++t)
#pragma unroll
            for (int h2 = 0; h2 < 2; ++h2)
                pk_[t][h2] = cvtpk(exp2f(st_[t][2 * h2]     * c - CM),
                                   exp2f(st_[t][2 * h2 + 1] * c - CM));
        unsigned int a0 = pk_[0][0], b0 = pk_[1][0];
        pl32swap(a0, b0); pl16swap(a0, b0);   // a0=ap0 pair j0, b0=pair j2
        unsigned int a1 = pk_[0][1], b1 = pk_[1][1];
        pl32swap(a1, b1); pl16swap(a1, b1);   // a1=pair j1, b1=pair j3
        unsigned int c0 = pk_[2][0], d0 = pk_[3][0];
        pl32swap(c0, d0); pl16swap(c0, d0);
        unsigned int c1 = pk_[2][1], d1 = pk_[3][1];
        pl32swap(c1, d1); pl16swap(c1, d1);
        short8 ap0 = pack4(a0, a1, b0, b1);   // P[q=r][k = 8*quad + 0..7]
        short8 ap1 = pack4(c0, c1, d0, d1);   // P[q=r][k = 32 + 8*quad + 0..7]
        // ---- PV + l from staged V tile
        {
            short8 va, vb;
            va = ld8(&vlds[s][0 * 16 + r][quad * 8]);
            vb = ld8(&vlds[s][0 * 16 + r][32 + quad * 8]);
            o0 = mfma16(ap0, va, o0);  o0 = mfma16(ap1, vb, o0);
            va = ld8(&vlds[s][1 * 16 + r][quad * 8]);
            vb = ld8(&vlds[s][1 * 16 + r][32 + quad * 8]);
            o1 = mfma16(ap0, va, o1);  o1 = mfma16(ap1, vb, o1);
            va = ld8(&vlds[s][2 * 16 + r][quad * 8]);
            vb = ld8(&vlds[s][2 * 16 + r][32 + quad * 8]);
            o2 = mfma16(ap0, va, o2);  o2 = mfma16(ap1, vb, o2);
            va = ld8(&vlds[s][3 * 16 + r][quad * 8]);
            vb = ld8(&vlds[s][3 * 16 + r][32 + quad * 8]);
            o3 = mfma16(ap0, va, o3);  o3 = mfma16(ap1, vb, o3);
            lacc = mfma16(ap0, ones, lacc);
            lacc = mfma16(ap1, ones, lacc);
        }
        if (it < 15) {
            int ns = s ^ 1;
            st8(&klds[ns][srow0][scol], pk0);
            st8(&klds[ns][srow1][scol], pk1);
            st8(&vlds[ns][srow0][scol], pv0);
            st8(&vlds[ns][srow1][scol], pv1);
        }
        __syncthreads();
    }

    unsigned short* ob = attn_out + (size_t)b * 1024 * 512 + (size_t)h * 64;
#pragma unroll
    for (int rr = 0; rr < 4; ++rr) {
        float inv = 1.0f / lacc[rr];
        int n = q0 + quad * 4 + rr;
        unsigned short* orow = ob + (size_t)n * 512 + r;
        orow[0]  = f2b(o0[rr] * inv);
        orow[16] = f2b(o1[rr] * inv);
        orow[32] = f2b(o2[rr] * inv);
        orow[48] = f2b(o3[rr] * inv);
    }
}

// ---------------------------------------------------------------------------
extern "C" void kernel_launch(void* const* d_in, const int* in_sizes, int n_in,
                              void* d_out, int out_size, void* d_ws, size_t ws_size,
                              hipStream_t stream)
{
    const float* x        = (const float*)d_in[0];
    const float* s        = (const float*)d_in[1];
    const float* k_weight = (const float*)d_in[2];
    const float* k_aff_w  = (const float*)d_in[3];
    const float* k_aff_b  = (const float*)d_in[4];
    const float* o_weight = (const float*)d_in[5];
    const float* o_aff_w  = (const float*)d_in[6];
    const float* o_aff_b  = (const float*)d_in[7];
    float* out = (float*)d_out;

    char* ws = (char*)d_ws;
    float* style          = (float*)ws;                                   // 32 KB
    unsigned short* wmod  = (unsigned short*)(ws + 32 * 1024);            // 8 MB (both maps)
    unsigned short* attn  = wmod + (size_t)2 * 8 * 512 * 512;             // 8 MB
    unsigned short* kqv   = attn + (size_t)8 * 1024 * 512;                // 8 MB
    unsigned short* vt    = kqv  + (size_t)8 * 1024 * 512;                // 8 MB

    style_kernel<<<2048, 256, 0, stream>>>(s, k_aff_w, k_aff_b, o_aff_w, o_aff_b, style);
    modw_kernel<<<2048, 256, 0, stream>>>(k_weight, o_weight, style, wmod);
    gemm_bt_lds_kernel<float, unsigned short, true><<<1024, 256, 0, stream>>>(x, wmod, kqv, vt);
    attn_kernel<<<1024, 256, 0, stream>>>(kqv, vt, attn);
    gemm_bt_lds_kernel<unsigned short, float, false><<<1024, 256, 0, stream>>>(attn, wmod + (size_t)8 * 512 * 512, out, nullptr);
}